// Round 16
// baseline (453.467 us; speedup 1.0000x reference)
//
#include <hip/hip_runtime.h>

// KCenterSampler FPS — barrier-free step loop: per-WAVE publish + all-lane
// LLC poll. The agent-scope LLC slot channel is the only proven cross-CU
// path (R6/R10/R13/R14 all failed to beat it); this round removes every
// cycle around it instead: no LDS exchange, no __syncthreads, no block
// combine — each wave DPP-reduces its 392-point partial, lane 0 publishes
// the wave max to one of 64 per-step slots, then all 64 lanes poll the 64
// slots (one each, self-contained loads) and butterfly-max -> far in every
// lane. Deterministic: slots are write-once per step, max is exact.
//
// Retained proven pieces: coords/sq/dist in VGPRs (waves_per_eu(1,1) +
// asm launder, VGPR=132), DPP reductions, packed (monotone-dist, NPTS-j)
// u64 keys (first-index tie-break), fused gather (sub==0 wave 0), memset-
// zeroed slots per launch. Arithmetic bit-identical to R1/3/4/8/9/13.

#define NPTS 6272
#define CDIM 35
#define BT   8
#define KSEL 128
#define THW  12544
#define BPS  16                  // blocks per segment
#define PPB  392                 // points per block
#define BLK  256
#define NB   (BT * BPS)          // 128 blocks
#define TAILN (PPB - BLK)        // 136: threads owning a 2nd point
#define SPS  64                  // slots per step = BPS * 4 waves

__device__ __forceinline__ unsigned long long key_of(float v, int j) {
  unsigned int u = __float_as_uint(v);
  u = (u & 0x80000000u) ? ~u : (u | 0x80000000u);   // monotone float->uint
  return ((unsigned long long)u << 32) | (unsigned int)(NPTS - j); // both words !=0
}
__device__ __forceinline__ unsigned long long kmax(unsigned long long a,
                                                   unsigned long long b) {
  return a > b ? a : b;
}

template <int CTRL, int RMASK, bool BC>
__device__ __forceinline__ unsigned long long dpp_kmax(unsigned long long k) {
  unsigned int lo = (unsigned int)k, hi = (unsigned int)(k >> 32);
  unsigned int tlo = (unsigned int)__builtin_amdgcn_update_dpp(0, (int)lo, CTRL, RMASK, 0xF, BC);
  unsigned int thi = (unsigned int)__builtin_amdgcn_update_dpp(0, (int)hi, CTRL, RMASK, 0xF, BC);
  unsigned long long t = ((unsigned long long)thi << 32) | tlo;
  return kmax(k, t);
}
// 64-lane max; result broadcast to all lanes via readlane(63)
__device__ __forceinline__ unsigned long long wave_kmax64(unsigned long long k) {
  k = dpp_kmax<0x111, 0xF, true >(k);   // row_shr:1
  k = dpp_kmax<0x112, 0xF, true >(k);   // row_shr:2
  k = dpp_kmax<0x114, 0xF, true >(k);   // row_shr:4
  k = dpp_kmax<0x118, 0xF, true >(k);   // row_shr:8
  k = dpp_kmax<0x142, 0xA, false>(k);   // row_bcast:15
  k = dpp_kmax<0x143, 0xC, false>(k);   // row_bcast:31
  unsigned int rlo = (unsigned int)__builtin_amdgcn_readlane((int)(unsigned int)k, 63);
  unsigned int rhi = (unsigned int)__builtin_amdgcn_readlane((int)(k >> 32), 63);
  return ((unsigned long long)rhi << 32) | rlo;
}

// self-contained LLC load (issue + wait in one asm block; "=&v" mandatory)
__device__ __forceinline__ unsigned long long load_llc(const unsigned long long* p) {
  unsigned long long r;
  asm volatile("global_load_dwordx2 %0, %1, off sc0 sc1\n\ts_waitcnt vmcnt(0)"
               : "=&v"(r) : "v"(p) : "memory");
  return r;
}

__global__ __attribute__((amdgpu_waves_per_eu(1, 1))) __launch_bounds__(BLK)
void fps_kernel(const float* __restrict__ x,
                const int* __restrict__ init_,
                float* __restrict__ patches,
                float* __restrict__ sidx,
                unsigned long long* __restrict__ slots) {
  const int bid  = (int)blockIdx.x;
  const int b    = bid & 7;            // segment: round-robin -> same XCD
  const int sub  = bid >> 3;           // sub-block 0..15 within segment
  const int tid  = (int)threadIdx.x;
  const int lane = tid & 63;
  const int wid  = tid >> 6;
  const int j0   = sub * PPB;
  const int td   = b & 1;
  const float* xg = x + (size_t)b * NPTS * CDIM;
  unsigned long long* seg = slots + (size_t)b * KSEL * SPS;

  // ---- one-time load: coords -> VGPRs (laundered), sq sequential ----
  float xr0[CDIM], xr1[CDIM];
  float sqr0, sqr1, df0, df1;
  {
    const float* src0 = xg + (size_t)(j0 + tid) * CDIM;
    float acc = 0.0f;
    {
#pragma clang fp contract(off)
#pragma unroll
      for (int c = 0; c < CDIM; ++c) { float v = src0[c]; xr0[c] = v; acc = acc + v * v; }
    }
    sqr0 = acc; df0 = 50000.0f;
    sqr1 = 0.0f; df1 = 50000.0f;
#pragma unroll
    for (int c = 0; c < CDIM; ++c) xr1[c] = 0.0f;
    if (tid < TAILN) {
      const float* src1 = xg + (size_t)(j0 + BLK + tid) * CDIM;
      float acc1 = 0.0f;
      {
#pragma clang fp contract(off)
#pragma unroll
        for (int c = 0; c < CDIM; ++c) { float v = src1[c]; xr1[c] = v; acc1 = acc1 + v * v; }
      }
      sqr1 = acc1;
    }
#pragma unroll
    for (int c = 0; c < CDIM; ++c) {
      asm volatile("" : "+v"(xr0[c]));
      asm volatile("" : "+v"(xr1[c]));
    }
    asm volatile("" : "+v"(sqr0));
    asm volatile("" : "+v"(sqr1));
  }

  int far;
  { int f = init_[b] % NPTS; if (f < 0) f += NPTS; far = f; }  // jnp.remainder
  if (sub == 0 && wid == 0) {          // fused output, row 0
    if (lane == 0) sidx[b * KSEL] = (float)(far + td * NPTS);
    if (lane < 32) patches[(size_t)(b * KSEL) * 32 + lane] = xg[(size_t)far * CDIM + lane];
  }

  // ---- 127 sequential FPS steps — NO barriers, NO LDS ----
  for (int step = 1; step < KSEL; ++step) {
    const int fu = __builtin_amdgcn_readfirstlane(far);
    const float* fx = xg + (size_t)fu * CDIM;
    float xf[CDIM];
#pragma unroll
    for (int c = 0; c < CDIM; ++c) xf[c] = fx[c];

    // sqf: sequential chain from identical f32 values -> bitwise equal
    float sqf;
    {
#pragma clang fp contract(off)
      float a = 0.0f;
#pragma unroll
      for (int c = 0; c < CDIM; ++c) { float t = xf[c]; a = a + t * t; }
      sqf = a;
    }

    // point 0 (all threads)
    unsigned long long bk;
    {
      float dot = 0.0f;
#pragma unroll
      for (int c = 0; c < CDIM; ++c)
        dot = __builtin_fmaf(xf[c], xr0[c], dot);          // k-sequential FMA
      float d2;
      {
#pragma clang fp contract(off)
        d2 = (sqf + sqr0) - 2.0f * dot;                    // reference order
      }
      d2 = fmaxf(d2, 0.0f);
      float d = __fsqrt_rn(d2);
      const int j = j0 + tid;
      d = (j == far) ? -1.0f : d;                          // diagonal = -1
      float nd = fminf(d, df0);                            // f32 min-carry
      df0 = nd;
      bk = key_of(nd, j);
    }
    // point 1 (threads 0..135)
    if (tid < TAILN) {
      float dot = 0.0f;
#pragma unroll
      for (int c = 0; c < CDIM; ++c)
        dot = __builtin_fmaf(xf[c], xr1[c], dot);
      float d2;
      {
#pragma clang fp contract(off)
        d2 = (sqf + sqr1) - 2.0f * dot;
      }
      d2 = fmaxf(d2, 0.0f);
      float d = __fsqrt_rn(d2);
      const int j = j0 + BLK + tid;
      d = (j == far) ? -1.0f : d;
      float nd = fminf(d, df1);
      df1 = nd;
      bk = kmax(bk, key_of(nd, j));
    }

    // per-wave publish: DPP max (broadcast), lane 0 stores the wave slot
    bk = wave_kmax64(bk);
    if (lane == 0)
      __hip_atomic_store(&seg[(size_t)step * SPS + sub * 4 + wid], bk,
                         __ATOMIC_RELAXED, __HIP_MEMORY_SCOPE_AGENT);
    asm volatile("" ::: "memory");     // keep store ahead of the poll

    // all-lane poll: lane i owns slot i (64 slots = 8 cachelines)
    unsigned long long k = 0ull;
    const unsigned long long* sp = &seg[(size_t)step * SPS + lane];
    while (__any(k == 0ull)) {
      if (k == 0ull) k = load_llc(sp);
    }
    k = wave_kmax64(k);                // winner broadcast to every lane
    far = NPTS - (int)(unsigned int)(k & 0xFFFFFFFFull);

    if (sub == 0 && wid == 0) {        // fused output row `step`
      if (lane == 0) sidx[b * KSEL + step] = (float)(far + td * NPTS);
      if (lane < 32) patches[(size_t)(b * KSEL + step) * 32 + lane] =
                         xg[(size_t)far * CDIM + lane];
    }
  }
}

extern "C" void kernel_launch(void* const* d_in, const int* in_sizes, int n_in,
                              void* d_out, int out_size, void* d_ws, size_t ws_size,
                              hipStream_t stream) {
  const float* x    = (const float*)d_in[0];
  const int*   init = (const int*)d_in[1];
  (void)in_sizes; (void)n_in; (void)out_size; (void)ws_size;

  // ws layout: slots [BT * KSEL * SPS u64] = 512 KiB
  unsigned long long* slots = (unsigned long long*)d_ws;
  const size_t slots_bytes = (size_t)BT * KSEL * SPS * sizeof(unsigned long long);

  float* patches = (float*)d_out;
  float* sidx    = patches + (size_t)4 * 256 * 32;

  hipMemsetAsync(d_ws, 0, slots_bytes, stream);   // zero slots per launch

  void* kargs[] = { (void*)&x, (void*)&init, (void*)&patches, (void*)&sidx,
                    (void*)&slots };
  hipLaunchCooperativeKernel((const void*)fps_kernel, dim3(NB), dim3(BLK),
                             kargs, 0, stream);
}

// Round 17
// 238.800 us; speedup vs baseline: 1.8989x; 1.8989x over previous
//
#include <hip/hip_runtime.h>

// KCenterSampler FPS — BPS=8 (traffic-minimized sync) + junk-strip.
//
// R14/R15 dose-response: agent-scope poll streams queue at the LLC fabric
// (R13 1x=193µs, R14 4x=211µs, R15 32x=433µs). This round goes BELOW R13:
// 8 blocks/segment -> 8 slots/step = ONE cache line, polled by 8 lanes of
// wave 0 only (64 polling waves chip-wide, 1/4 of R13's traffic).
// Each block owns 784 points: 3 register chains/thread + 16-thread tail
// (~140 coord VGPRs, fits 512 budget at waves_per_eu(1,1), 1 block/CU).
// Removed: probe array, scalar/sleep junk, ready-barrier (all dead per
// R13/R14). Gather runs on wave 1 so polling wave 0 carries no stores.
// Sync protocol itself is byte-equivalent to R4/R13's proven channel:
// barrier1 -> tid0 agent-scope u64 store -> wave-0 poll -> far_s -> barrier2.
// Arithmetic bit-identical to R1/3/4/8/9/13 (absmax 0).

#define NPTS 6272
#define CDIM 35
#define BT   8
#define KSEL 128
#define THW  12544
#define BPS  8                   // blocks per segment (1 slot line/step)
#define PPB  784                 // points per block
#define BLK  256
#define NB   (BT * BPS)          // 64 blocks
#define TAIL4 16                 // threads 0..15 own a 4th point

__device__ __forceinline__ unsigned long long key_of(float v, int j) {
  unsigned int u = __float_as_uint(v);
  u = (u & 0x80000000u) ? ~u : (u | 0x80000000u);   // monotone float->uint
  return ((unsigned long long)u << 32) | (unsigned int)(NPTS - j); // both words !=0
}
__device__ __forceinline__ unsigned long long kmax(unsigned long long a,
                                                   unsigned long long b) {
  return a > b ? a : b;
}

template <int CTRL, int RMASK, bool BC>
__device__ __forceinline__ unsigned long long dpp_kmax(unsigned long long k) {
  unsigned int lo = (unsigned int)k, hi = (unsigned int)(k >> 32);
  unsigned int tlo = (unsigned int)__builtin_amdgcn_update_dpp(0, (int)lo, CTRL, RMASK, 0xF, BC);
  unsigned int thi = (unsigned int)__builtin_amdgcn_update_dpp(0, (int)hi, CTRL, RMASK, 0xF, BC);
  unsigned long long t = ((unsigned long long)thi << 32) | tlo;
  return kmax(k, t);
}
// 64-lane max, result broadcast to all lanes (full exec only)
__device__ __forceinline__ unsigned long long wave_kmax64(unsigned long long k) {
  k = dpp_kmax<0x111, 0xF, true >(k);   // row_shr:1
  k = dpp_kmax<0x112, 0xF, true >(k);   // row_shr:2
  k = dpp_kmax<0x114, 0xF, true >(k);   // row_shr:4
  k = dpp_kmax<0x118, 0xF, true >(k);   // row_shr:8
  k = dpp_kmax<0x142, 0xA, false>(k);   // row_bcast:15
  k = dpp_kmax<0x143, 0xC, false>(k);   // row_bcast:31
  unsigned int rlo = (unsigned int)__builtin_amdgcn_readlane((int)(unsigned int)k, 63);
  unsigned int rhi = (unsigned int)__builtin_amdgcn_readlane((int)(k >> 32), 63);
  return ((unsigned long long)rhi << 32) | rlo;
}
// max over lanes 0..7 (exec = tid<8); lane7 accumulates, broadcast via readlane
__device__ __forceinline__ unsigned long long row8_kmax(unsigned long long k) {
  k = dpp_kmax<0x111, 0xF, true>(k);    // lane i = max(i-1..i)
  k = dpp_kmax<0x112, 0xF, true>(k);    // lane i = max(i-3..i)
  k = dpp_kmax<0x114, 0xF, true>(k);    // lane i = max(i-7..i); lane7 = max(0..7)
  unsigned int rlo = (unsigned int)__builtin_amdgcn_readlane((int)(unsigned int)k, 7);
  unsigned int rhi = (unsigned int)__builtin_amdgcn_readlane((int)(k >> 32), 7);
  return ((unsigned long long)rhi << 32) | rlo;
}

// self-contained LLC load (issue + wait in one asm block; "=&v" mandatory)
__device__ __forceinline__ unsigned long long load_llc(const unsigned long long* p) {
  unsigned long long r;
  asm volatile("global_load_dwordx2 %0, %1, off sc0 sc1\n\ts_waitcnt vmcnt(0)"
               : "=&v"(r) : "v"(p) : "memory");
  return r;
}

__global__ __attribute__((amdgpu_waves_per_eu(1, 1))) __launch_bounds__(BLK)
void fps_kernel(const float* __restrict__ x,
                const int* __restrict__ init_,
                float* __restrict__ patches,
                float* __restrict__ sidx,
                unsigned long long* __restrict__ slots) {
  __shared__ unsigned long long wk[4];
  __shared__ int far_s;

  const int bid  = (int)blockIdx.x;
  const int b    = bid & 7;            // segment: round-robin -> same XCD
  const int sub  = bid >> 3;           // sub-block 0..7 within segment
  const int tid  = (int)threadIdx.x;
  const int lane = tid & 63;
  const int wid  = tid >> 6;
  const int j0   = sub * PPB;
  const int td   = b & 1;
  const float* xg = x + (size_t)b * NPTS * CDIM;
  unsigned long long* seg = slots + (size_t)b * KSEL * BPS;

  // ---- one-time load: coords -> VGPRs (laundered), sq sequential ----
  float xr0[CDIM], xr1[CDIM], xr2[CDIM], xr3[CDIM];
  float sqr0, sqr1, sqr2, sqr3, df0, df1, df2, df3;
  {
    const float* s0 = xg + (size_t)(j0 + tid) * CDIM;
    const float* s1 = xg + (size_t)(j0 + 256 + tid) * CDIM;
    const float* s2 = xg + (size_t)(j0 + 512 + tid) * CDIM;
    float a0 = 0.0f, a1 = 0.0f, a2 = 0.0f;
    {
#pragma clang fp contract(off)
#pragma unroll
      for (int c = 0; c < CDIM; ++c) {
        float v0 = s0[c]; xr0[c] = v0; a0 = a0 + v0 * v0;
        float v1 = s1[c]; xr1[c] = v1; a1 = a1 + v1 * v1;
        float v2 = s2[c]; xr2[c] = v2; a2 = a2 + v2 * v2;
      }
    }
    sqr0 = a0; sqr1 = a1; sqr2 = a2;
    df0 = df1 = df2 = df3 = 50000.0f;    // FILL_DIST
    sqr3 = 0.0f;
#pragma unroll
    for (int c = 0; c < CDIM; ++c) xr3[c] = 0.0f;
    if (tid < TAIL4) {
      const float* s3 = xg + (size_t)(j0 + 768 + tid) * CDIM;
      float a3 = 0.0f;
      {
#pragma clang fp contract(off)
#pragma unroll
        for (int c = 0; c < CDIM; ++c) { float v = s3[c]; xr3[c] = v; a3 = a3 + v * v; }
      }
      sqr3 = a3;
    }
#pragma unroll
    for (int c = 0; c < CDIM; ++c) {
      asm volatile("" : "+v"(xr0[c]));
      asm volatile("" : "+v"(xr1[c]));
      asm volatile("" : "+v"(xr2[c]));
      asm volatile("" : "+v"(xr3[c]));
    }
    asm volatile("" : "+v"(sqr0));
    asm volatile("" : "+v"(sqr1));
    asm volatile("" : "+v"(sqr2));
    asm volatile("" : "+v"(sqr3));
  }

  int far;
  { int f = init_[b] % NPTS; if (f < 0) f += NPTS; far = f; }  // jnp.remainder
  if (sub == 0 && wid == 1) {          // fused output row 0 (wave 1: not the poller)
    if (lane == 0) sidx[b * KSEL] = (float)(far + td * NPTS);
    if (lane < 32) patches[(size_t)(b * KSEL) * 32 + lane] = xg[(size_t)far * CDIM + lane];
  }

  // ---- 127 sequential FPS steps ----
  for (int step = 1; step < KSEL; ++step) {
    const int fu = __builtin_amdgcn_readfirstlane(far);
    const float* fx = xg + (size_t)fu * CDIM;
    float xf[CDIM];
#pragma unroll
    for (int c = 0; c < CDIM; ++c) xf[c] = fx[c];

    // sqf: sequential chain from identical f32 values -> bitwise equal
    float sqf;
    {
#pragma clang fp contract(off)
      float a = 0.0f;
#pragma unroll
      for (int c = 0; c < CDIM; ++c) { float t = xf[c]; a = a + t * t; }
      sqf = a;
    }

    // three full chains (ILP-interleaved by the compiler)
    float dot0 = 0.0f, dot1 = 0.0f, dot2 = 0.0f;
#pragma unroll
    for (int c = 0; c < CDIM; ++c) {
      dot0 = __builtin_fmaf(xf[c], xr0[c], dot0);          // k-sequential FMA
      dot1 = __builtin_fmaf(xf[c], xr1[c], dot1);
      dot2 = __builtin_fmaf(xf[c], xr2[c], dot2);
    }
    unsigned long long bk;
    {
      float d2;
      {
#pragma clang fp contract(off)
        d2 = (sqf + sqr0) - 2.0f * dot0;                   // reference order
      }
      d2 = fmaxf(d2, 0.0f);
      float d = __fsqrt_rn(d2);
      const int j = j0 + tid;
      d = (j == far) ? -1.0f : d;                          // diagonal = -1
      float nd = fminf(d, df0); df0 = nd;                  // f32 min-carry
      bk = key_of(nd, j);
    }
    {
      float d2;
      {
#pragma clang fp contract(off)
        d2 = (sqf + sqr1) - 2.0f * dot1;
      }
      d2 = fmaxf(d2, 0.0f);
      float d = __fsqrt_rn(d2);
      const int j = j0 + 256 + tid;
      d = (j == far) ? -1.0f : d;
      float nd = fminf(d, df1); df1 = nd;
      bk = kmax(bk, key_of(nd, j));
    }
    {
      float d2;
      {
#pragma clang fp contract(off)
        d2 = (sqf + sqr2) - 2.0f * dot2;
      }
      d2 = fmaxf(d2, 0.0f);
      float d = __fsqrt_rn(d2);
      const int j = j0 + 512 + tid;
      d = (j == far) ? -1.0f : d;
      float nd = fminf(d, df2); df2 = nd;
      bk = kmax(bk, key_of(nd, j));
    }
    if (tid < TAIL4) {
      float dot3 = 0.0f;
#pragma unroll
      for (int c = 0; c < CDIM; ++c)
        dot3 = __builtin_fmaf(xf[c], xr3[c], dot3);
      float d2;
      {
#pragma clang fp contract(off)
        d2 = (sqf + sqr3) - 2.0f * dot3;
      }
      d2 = fmaxf(d2, 0.0f);
      float d = __fsqrt_rn(d2);
      const int j = j0 + 768 + tid;
      d = (j == far) ? -1.0f : d;
      float nd = fminf(d, df3); df3 = nd;
      bk = kmax(bk, key_of(nd, j));
    }

    // wave max via DPP; lane 0 parks it in LDS
    bk = wave_kmax64(bk);
    if (lane == 0) wk[wid] = bk;
    __syncthreads();                                       // barrier 1

    if (tid < BPS) {                                       // wave 0, lanes 0..7
      if (tid == 0) {
        unsigned long long m = kmax(kmax(wk[0], wk[1]), kmax(wk[2], wk[3]));
        __hip_atomic_store(&seg[step * BPS + sub], m,      // R4-proven channel
                           __ATOMIC_RELAXED, __HIP_MEMORY_SCOPE_AGENT);
      }
      asm volatile("" ::: "memory");   // keep store ahead of the poll
      // tight serial poll: 8 lanes, ONE cache line per segment per step
      unsigned long long k = 0ull;
      const unsigned long long* sp = &seg[step * BPS + tid];
      do {
        if (k == 0ull) k = load_llc(sp);
      } while (__any(k == 0ull));
      k = row8_kmax(k);
      if (tid == 0)
        far_s = NPTS - (int)(unsigned int)(k & 0xFFFFFFFFull);
    }
    __syncthreads();                                       // barrier 2
    far = far_s;

    if (sub == 0 && wid == 1) {        // fused output row `step` (wave 1)
      if (lane == 0) sidx[b * KSEL + step] = (float)(far + td * NPTS);
      if (lane < 32) patches[(size_t)(b * KSEL + step) * 32 + lane] =
                         xg[(size_t)far * CDIM + lane];
    }
  }
}

extern "C" void kernel_launch(void* const* d_in, const int* in_sizes, int n_in,
                              void* d_out, int out_size, void* d_ws, size_t ws_size,
                              hipStream_t stream) {
  const float* x    = (const float*)d_in[0];
  const int*   init = (const int*)d_in[1];
  (void)in_sizes; (void)n_in; (void)out_size; (void)ws_size;

  // ws layout: slots [BT * KSEL * BPS u64] = 64 KiB
  unsigned long long* slots = (unsigned long long*)d_ws;
  const size_t slots_bytes = (size_t)BT * KSEL * BPS * sizeof(unsigned long long);

  float* patches = (float*)d_out;
  float* sidx    = patches + (size_t)4 * 256 * 32;

  hipMemsetAsync(d_ws, 0, slots_bytes, stream);   // zero slots per launch

  void* kargs[] = { (void*)&x, (void*)&init, (void*)&patches, (void*)&sidx,
                    (void*)&slots };
  hipLaunchCooperativeKernel((const void*)fps_kernel, dim3(NB), dim3(BLK),
                             kargs, 0, stream);
}

// Round 18
// 220.234 us; speedup vs baseline: 2.0590x; 1.0843x over previous
//
#include <hip/hip_runtime.h>

// KCenterSampler FPS — consolidated best-known configuration.
// = R12's depth-3 pipelined LLC poll (proven) + R13's fused gather (proven),
// dead experiments removed (probe channel, scalar K$ poll, s_sleep, latches,
// ready-barrier). Sync-channel conclusion after R6/R10/R13/R14/R15/R16:
// the agent-scope LLC slot exchange at BPS=16 with bid&7 co-location is the
// only working cross-CU path, and its traffic level sits below the fabric
// congestion knee (dose-response 0.25x=214, 1x=193.6, 4x=211, 32x=433 µs).
//
// Structure: 8 segments x 16 blocks (cooperative, b=bid&7 -> one XCD/segment,
// makes the per-step xf broadcast an L2 hit). Coords/sq/dist in VGPRs
// (waves_per_eu(1,1) + asm launder). Per step: register distance update,
// wave DPP max, LDS combine, tid0 agent-scope u64 publish, 16-lane depth-3
// pipelined poll (write-once slots, per-word v_max_u32 merge), 16-lane DPP
// reduce, far_s broadcast. Fused output on wave 1 of sub==0.
// Arithmetic bit-identical to R1/3/4/8/9/12/13 (absmax 0).

#define NPTS 6272
#define CDIM 35
#define BT   8
#define KSEL 128
#define THW  12544
#define BPS  16                  // blocks per segment
#define PPB  392                 // points per block
#define BLK  256
#define NB   (BT * BPS)          // 128 blocks
#define TAILN (PPB - BLK)        // 136: threads owning a 2nd point

__device__ __forceinline__ unsigned long long key_of(float v, int j) {
  unsigned int u = __float_as_uint(v);
  u = (u & 0x80000000u) ? ~u : (u | 0x80000000u);   // monotone float->uint
  return ((unsigned long long)u << 32) | (unsigned int)(NPTS - j); // both words !=0
}
__device__ __forceinline__ unsigned long long kmax(unsigned long long a,
                                                   unsigned long long b) {
  return a > b ? a : b;
}

template <int CTRL, int RMASK, bool BC>
__device__ __forceinline__ unsigned long long dpp_kmax(unsigned long long k) {
  unsigned int lo = (unsigned int)k, hi = (unsigned int)(k >> 32);
  unsigned int tlo = (unsigned int)__builtin_amdgcn_update_dpp(0, (int)lo, CTRL, RMASK, 0xF, BC);
  unsigned int thi = (unsigned int)__builtin_amdgcn_update_dpp(0, (int)hi, CTRL, RMASK, 0xF, BC);
  unsigned long long t = ((unsigned long long)thi << 32) | tlo;
  return kmax(k, t);
}
// 64-lane max -> broadcast (full exec only)
__device__ __forceinline__ unsigned long long wave_kmax64(unsigned long long k) {
  k = dpp_kmax<0x111, 0xF, true >(k);   // row_shr:1
  k = dpp_kmax<0x112, 0xF, true >(k);   // row_shr:2
  k = dpp_kmax<0x114, 0xF, true >(k);   // row_shr:4
  k = dpp_kmax<0x118, 0xF, true >(k);   // row_shr:8
  k = dpp_kmax<0x142, 0xA, false>(k);   // row_bcast:15
  k = dpp_kmax<0x143, 0xC, false>(k);   // row_bcast:31
  unsigned int rlo = (unsigned int)__builtin_amdgcn_readlane((int)(unsigned int)k, 63);
  unsigned int rhi = (unsigned int)__builtin_amdgcn_readlane((int)(k >> 32), 63);
  return ((unsigned long long)rhi << 32) | rlo;
}
// max over lanes 0..15 (exec = tid<16)
__device__ __forceinline__ unsigned long long row16_kmax(unsigned long long k) {
  k = dpp_kmax<0x111, 0xF, true>(k);
  k = dpp_kmax<0x112, 0xF, true>(k);
  k = dpp_kmax<0x114, 0xF, true>(k);
  k = dpp_kmax<0x118, 0xF, true>(k);
  unsigned int rlo = (unsigned int)__builtin_amdgcn_readlane((int)(unsigned int)k, 15);
  unsigned int rhi = (unsigned int)__builtin_amdgcn_readlane((int)(k >> 32), 15);
  return ((unsigned long long)rhi << 32) | rlo;
}

// depth-3 pipelined LLC poll of one u64 slot (write-once 0->key; per-word
// v_max_u32 merge is exact). Exit when min(lo,hi)!=0; drains vmcnt(0).
__device__ __forceinline__ unsigned long long poll_slot(const unsigned long long* p) {
  unsigned int klo = 0u, khi = 0u;
  unsigned int a0, b0, a1, b1, a2, b2, t;
  asm volatile(
      "global_load_dword %[a0], %[ad], off sc0 sc1\n\t"
      "global_load_dword %[b0], %[ad], off offset:4 sc0 sc1\n\t"
      "global_load_dword %[a1], %[ad], off sc0 sc1\n\t"
      "global_load_dword %[b1], %[ad], off offset:4 sc0 sc1\n\t"
      "global_load_dword %[a2], %[ad], off sc0 sc1\n\t"
      "global_load_dword %[b2], %[ad], off offset:4 sc0 sc1\n\t"
      "1:\n\t"
      "s_waitcnt vmcnt(4)\n\t"
      "v_max_u32 %[klo], %[klo], %[a0]\n\t"
      "v_max_u32 %[khi], %[khi], %[b0]\n\t"
      "global_load_dword %[a0], %[ad], off sc0 sc1\n\t"
      "global_load_dword %[b0], %[ad], off offset:4 sc0 sc1\n\t"
      "v_min_u32 %[t], %[klo], %[khi]\n\t"
      "v_cmp_eq_u32 vcc, 0, %[t]\n\t"
      "s_cbranch_vccz 9f\n\t"
      "s_waitcnt vmcnt(4)\n\t"
      "v_max_u32 %[klo], %[klo], %[a1]\n\t"
      "v_max_u32 %[khi], %[khi], %[b1]\n\t"
      "global_load_dword %[a1], %[ad], off sc0 sc1\n\t"
      "global_load_dword %[b1], %[ad], off offset:4 sc0 sc1\n\t"
      "v_min_u32 %[t], %[klo], %[khi]\n\t"
      "v_cmp_eq_u32 vcc, 0, %[t]\n\t"
      "s_cbranch_vccz 9f\n\t"
      "s_waitcnt vmcnt(4)\n\t"
      "v_max_u32 %[klo], %[klo], %[a2]\n\t"
      "v_max_u32 %[khi], %[khi], %[b2]\n\t"
      "global_load_dword %[a2], %[ad], off sc0 sc1\n\t"
      "global_load_dword %[b2], %[ad], off offset:4 sc0 sc1\n\t"
      "v_min_u32 %[t], %[klo], %[khi]\n\t"
      "v_cmp_eq_u32 vcc, 0, %[t]\n\t"
      "s_cbranch_vccnz 1b\n\t"
      "9:\n\t"
      "s_waitcnt vmcnt(0)"
      : [klo] "+v"(klo), [khi] "+v"(khi),
        [a0] "=&v"(a0), [b0] "=&v"(b0), [a1] "=&v"(a1), [b1] "=&v"(b1),
        [a2] "=&v"(a2), [b2] "=&v"(b2), [t] "=&v"(t)
      : [ad] "v"(p)
      : "vcc", "memory");
  return ((unsigned long long)khi << 32) | klo;
}

__global__ __attribute__((amdgpu_waves_per_eu(1, 1))) __launch_bounds__(BLK)
void fps_kernel(const float* __restrict__ x,
                const int* __restrict__ init_,
                float* __restrict__ patches,
                float* __restrict__ sidx,
                unsigned long long* __restrict__ slots) {
  __shared__ unsigned long long wk[4];
  __shared__ int far_s;

  const int bid  = (int)blockIdx.x;
  const int b    = bid & 7;            // segment: round-robin -> same XCD
  const int sub  = bid >> 3;           // sub-block 0..15 within segment
  const int tid  = (int)threadIdx.x;
  const int lane = tid & 63;
  const int wid  = tid >> 6;
  const int j0   = sub * PPB;
  const int td   = b & 1;
  const float* xg = x + (size_t)b * NPTS * CDIM;
  unsigned long long* seg = slots + (size_t)b * KSEL * BPS;

  // ---- one-time load: coords -> VGPRs (laundered), sq sequential ----
  float xr0[CDIM], xr1[CDIM];
  float sqr0, sqr1, df0, df1;
  {
    const float* src0 = xg + (size_t)(j0 + tid) * CDIM;
    float acc = 0.0f;
    {
#pragma clang fp contract(off)
#pragma unroll
      for (int c = 0; c < CDIM; ++c) { float v = src0[c]; xr0[c] = v; acc = acc + v * v; }
    }
    sqr0 = acc; df0 = 50000.0f;
    sqr1 = 0.0f; df1 = 50000.0f;
#pragma unroll
    for (int c = 0; c < CDIM; ++c) xr1[c] = 0.0f;
    if (tid < TAILN) {
      const float* src1 = xg + (size_t)(j0 + BLK + tid) * CDIM;
      float acc1 = 0.0f;
      {
#pragma clang fp contract(off)
#pragma unroll
        for (int c = 0; c < CDIM; ++c) { float v = src1[c]; xr1[c] = v; acc1 = acc1 + v * v; }
      }
      sqr1 = acc1;
    }
#pragma unroll
    for (int c = 0; c < CDIM; ++c) {
      asm volatile("" : "+v"(xr0[c]));
      asm volatile("" : "+v"(xr1[c]));
    }
    asm volatile("" : "+v"(sqr0));
    asm volatile("" : "+v"(sqr1));
  }

  int far;
  { int f = init_[b] % NPTS; if (f < 0) f += NPTS; far = f; }  // jnp.remainder
  if (sub == 0 && wid == 1) {          // fused output row 0 (wave 1, not poller)
    if (lane == 0) sidx[b * KSEL] = (float)(far + td * NPTS);
    if (lane < 32) patches[(size_t)(b * KSEL) * 32 + lane] = xg[(size_t)far * CDIM + lane];
  }

  // ---- 127 sequential FPS steps ----
  for (int step = 1; step < KSEL; ++step) {
    const int fu = __builtin_amdgcn_readfirstlane(far);
    const float* fx = xg + (size_t)fu * CDIM;
    float xf[CDIM];
#pragma unroll
    for (int c = 0; c < CDIM; ++c) xf[c] = fx[c];

    // sqf: sequential chain from identical f32 values -> bitwise equal
    float sqf;
    {
#pragma clang fp contract(off)
      float a = 0.0f;
#pragma unroll
      for (int c = 0; c < CDIM; ++c) { float t = xf[c]; a = a + t * t; }
      sqf = a;
    }

    // point 0 (all threads)
    unsigned long long bk;
    {
      float dot = 0.0f;
#pragma unroll
      for (int c = 0; c < CDIM; ++c)
        dot = __builtin_fmaf(xf[c], xr0[c], dot);          // k-sequential FMA
      float d2;
      {
#pragma clang fp contract(off)
        d2 = (sqf + sqr0) - 2.0f * dot;                    // reference order
      }
      d2 = fmaxf(d2, 0.0f);
      float d = __fsqrt_rn(d2);
      const int j = j0 + tid;
      d = (j == far) ? -1.0f : d;                          // diagonal = -1
      float nd = fminf(d, df0);                            // f32 min-carry
      df0 = nd;
      bk = key_of(nd, j);
    }
    // point 1 (threads 0..135)
    if (tid < TAILN) {
      float dot = 0.0f;
#pragma unroll
      for (int c = 0; c < CDIM; ++c)
        dot = __builtin_fmaf(xf[c], xr1[c], dot);
      float d2;
      {
#pragma clang fp contract(off)
        d2 = (sqf + sqr1) - 2.0f * dot;
      }
      d2 = fmaxf(d2, 0.0f);
      float d = __fsqrt_rn(d2);
      const int j = j0 + BLK + tid;
      d = (j == far) ? -1.0f : d;
      float nd = fminf(d, df1);
      df1 = nd;
      bk = kmax(bk, key_of(nd, j));
    }

    // wave max via DPP; lane 0 parks it in LDS
    bk = wave_kmax64(bk);
    if (lane == 0) wk[wid] = bk;
    __syncthreads();                                       // barrier 1

    if (tid < BPS) {
      if (tid == 0) {
        unsigned long long m = kmax(kmax(wk[0], wk[1]), kmax(wk[2], wk[3]));
        __hip_atomic_store(&seg[step * BPS + sub], m,      // R4-proven channel
                           __ATOMIC_RELAXED, __HIP_MEMORY_SCOPE_AGENT);
      }
      asm volatile("" ::: "memory");   // keep store ahead of the poll
      unsigned long long k = poll_slot(&seg[step * BPS + tid]);
      k = row16_kmax(k);
      if (tid == 0)
        far_s = NPTS - (int)(unsigned int)(k & 0xFFFFFFFFull);
    }
    __syncthreads();                                       // barrier 2
    far = far_s;

    if (sub == 0 && wid == 1) {        // fused output row `step` (wave 1)
      if (lane == 0) sidx[b * KSEL + step] = (float)(far + td * NPTS);
      if (lane < 32) patches[(size_t)(b * KSEL + step) * 32 + lane] =
                         xg[(size_t)far * CDIM + lane];
    }
  }
}

extern "C" void kernel_launch(void* const* d_in, const int* in_sizes, int n_in,
                              void* d_out, int out_size, void* d_ws, size_t ws_size,
                              hipStream_t stream) {
  const float* x    = (const float*)d_in[0];
  const int*   init = (const int*)d_in[1];
  (void)in_sizes; (void)n_in; (void)out_size; (void)ws_size;

  // ws layout: slots [BT * KSEL * BPS u64] = 128 KiB
  unsigned long long* slots = (unsigned long long*)d_ws;
  const size_t slots_bytes = (size_t)BT * KSEL * BPS * sizeof(unsigned long long);

  float* patches = (float*)d_out;
  float* sidx    = patches + (size_t)4 * 256 * 32;

  hipMemsetAsync(d_ws, 0, slots_bytes, stream);   // zero slots per launch

  void* kargs[] = { (void*)&x, (void*)&init, (void*)&patches, (void*)&sidx,
                    (void*)&slots };
  hipLaunchCooperativeKernel((const void*)fps_kernel, dim3(NB), dim3(BLK),
                             kargs, 0, stream);
}